// Round 3
// baseline (8764.571 us; speedup 1.0000x reference)
//
#include <hip/hip_runtime.h>
#include <hip/hip_cooperative_groups.h>
#include <cmath>

namespace cg = cooperative_groups;

#define T_STEPS 512
#define NBLK 128
#define FLAG_STRIDE 16  // 64B-padded flag slots

typedef _Float16 h8 __attribute__((ext_vector_type(8)));
typedef float f4 __attribute__((ext_vector_type(4)));

// ---------------- pack P = emb @ [Wx interleaved] + bias : [513][4096] fp32 (exact input path)
__global__ void pack_P(const float* __restrict__ emb,
                       const float* __restrict__ Wgx, const float* __restrict__ Wix,
                       const float* __restrict__ Wfx, const float* __restrict__ Wox,
                       const float* __restrict__ bg, const float* __restrict__ bi,
                       const float* __restrict__ bf_, const float* __restrict__ bo,
                       float* __restrict__ P) {
  __shared__ float es[8][512];
  const int vg = blockIdx.x;   // 0..64
  const int st = blockIdx.y;   // 0..15
  const int tid = threadIdx.x;
  for (int i = tid; i < 8 * 512; i += 256) {
    int vv = i >> 9, k = i & 511;
    int v = vg * 8 + vv;
    es[vv][k] = (v < 513) ? emb[v * 512 + k] : 0.f;
  }
  __syncthreads();
  const int c = st * 256 + tid;
  const int gate = c & 3, unit = c >> 2;
  const float* W = gate == 0 ? Wgx : gate == 1 ? Wix : gate == 2 ? Wfx : Wox;
  const float* bias = gate == 0 ? bg : gate == 1 ? bi : gate == 2 ? bf_ : bo;
  float acc[8];
  const float bv = bias[unit];
#pragma unroll
  for (int vv = 0; vv < 8; vv++) acc[vv] = bv;
  for (int k = 0; k < 512; k++) {
    float w = W[k * 1024 + unit];
#pragma unroll
    for (int vv = 0; vv < 8; vv++) acc[vv] += es[vv][k] * w;
  }
#pragma unroll
  for (int vv = 0; vv < 8; vv++) {
    int v = vg * 8 + vv;
    if (v < 513) P[(size_t)v * 4096 + c] = acc[vv];
  }
}

// ---------------- pack Wt[c][k] = W_{gate(c)}h[k][unit(c)] as fp16
__global__ void pack_Wt(const float* __restrict__ Wgh, const float* __restrict__ Wih,
                        const float* __restrict__ Wfh, const float* __restrict__ Woh,
                        _Float16* __restrict__ Wt) {
  const int c = blockIdx.x;
  const int gate = c & 3, unit = c >> 2;
  const float* W = gate == 0 ? Wgh : gate == 1 ? Wih : gate == 2 ? Wfh : Woh;
  for (int k = threadIdx.x; k < 1024; k += 256)
    Wt[(size_t)c * 1024 + k] = (_Float16)W[k * 1024 + unit];
}

// ---------------- persistent LSTM: 128 blocks x 512 threads
// Protocol per step: sc1 atomic h-stores -> syncthreads (vmcnt drain) -> relaxed
// agent flag store -> spin on 128 flags -> syncthreads -> acquire fence (buffer_inv).
// No release fence / wbl2 anywhere on the critical path.
__launch_bounds__(512)
__global__ void lstm_step_all(const int* __restrict__ x,
                              const float* __restrict__ P,
                              const _Float16* __restrict__ Wt,
                              _Float16* __restrict__ hbuf,
                              float* __restrict__ h32,
                              const float* __restrict__ h_init,
                              const float* __restrict__ c_init,
                              unsigned int* __restrict__ flags) {
  cg::grid_group grid = cg::this_grid();
  __shared__ _Float16 wlds[32 * 1024];  // 64 KB, XOR-swizzled granules
  __shared__ float pre[128][36];        // 18.4 KB
  __shared__ int xs2[2][128];
  const int tid = threadIdx.x;
  const int blk = blockIdx.x;
  const int lane = tid & 63;
  const int wid = tid >> 6;
  const int colbase = blk * 32;

  if (tid == 0)
    __hip_atomic_store(&flags[blk * FLAG_STRIDE], 0u, __ATOMIC_RELAXED, __HIP_MEMORY_SCOPE_AGENT);

  // stage time-invariant B slice (32 cols x 1024 k) into LDS, XOR-swizzled:
  // element (c, k) stored at wlds[c*1024 + (k ^ ((c&7)*8))], 16B granule granularity
  for (int i = tid; i < 32 * 128; i += 512) {
    int c = i >> 7, g = i & 127;
    *(h8*)&wlds[c * 1024 + ((g * 8) ^ ((c & 7) * 8))] =
        *(const h8*)&Wt[(size_t)(colbase + c) * 1024 + g * 8];
  }

  // per-thread persistent c state: thread owns (row=tid>>2, units 2*(tid&3)+{0,1})
  const int urow = tid >> 2;
  const int upair = tid & 3;
  const int ug0 = blk * 8 + upair * 2;
  float c0 = c_init[ug0], c1 = c_init[ug0 + 1];
  {
    union { _Float16 h[2]; unsigned int u; } pk;
    pk.h[0] = (_Float16)h_init[ug0];
    pk.h[1] = (_Float16)h_init[ug0 + 1];
    *(unsigned int*)&hbuf[urow * 1024 + ug0] = pk.u;  // buffer 0
  }
  if (tid < 128) xs2[0][tid] = x[tid * 513 + 0];
  grid.sync();  // once at init: covers h-init, wlds, flag reset, xs2[0]

  const int l15 = lane & 15;
  const int kg = (lane >> 4) * 8;
  const int arow = wid * 16 + l15;
  const int bx = (l15 & 7) * 8;  // LDS read-side XOR

  for (int t = 0; t < T_STEPS; t++) {
    const _Float16* hc = hbuf + (t & 1) * (128 * 1024);
    _Float16* hn = hbuf + ((t + 1) & 1) * (128 * 1024);

    // exact-P gather issued at loop top; latency hides under MFMA phase
    const float* prow = P + (size_t)xs2[t & 1][urow] * 4096 + colbase + upair * 8;
    f4 pv0 = *(const f4*)(prow);
    f4 pv1 = *(const f4*)(prow + 4);

    // recurrent GEMM: wave computes 16 rows x 32 cols, K=1024
    f4 acc0 = {0.f, 0.f, 0.f, 0.f}, acc1 = {0.f, 0.f, 0.f, 0.f};
    const _Float16* ap = hc + arow * 1024 + kg;
#pragma unroll 8
    for (int k0 = 0; k0 < 1024; k0 += 32) {
      h8 a = *(const h8*)(ap + k0);
      h8 b0 = *(const h8*)&wlds[l15 * 1024 + ((kg + k0) ^ bx)];
      h8 b1 = *(const h8*)&wlds[(l15 + 16) * 1024 + ((kg + k0) ^ bx)];
      acc0 = __builtin_amdgcn_mfma_f32_16x16x32_f16(a, b0, acc0, 0, 0, 0);
      acc1 = __builtin_amdgcn_mfma_f32_16x16x32_f16(a, b1, acc1, 0, 0, 0);
    }

#pragma unroll
    for (int r = 0; r < 4; r++) {
      int row = wid * 16 + (lane >> 4) * 4 + r;
      pre[row][l15] = acc0[r];
      pre[row][l15 + 16] = acc1[r];
    }
    // prefetch next step's x indices into the other xs2 buffer
    if (t + 1 < T_STEPS && tid < 128) xs2[(t + 1) & 1][tid] = x[tid * 513 + (t + 1)];
    __syncthreads();

    // gate nonlinearity + state update
    {
      f4 q0 = *(const f4*)&pre[urow][upair * 8];
      f4 q1 = *(const f4*)&pre[urow][upair * 8 + 4];
      float g0 = tanhf(pv0[0] + q0[0]);
      float i0 = 1.f / (1.f + expf(-(pv0[1] + q0[1])));
      float f0 = 1.f / (1.f + expf(-(pv0[2] + q0[2])));
      float o0 = 1.f / (1.f + expf(-(pv0[3] + q0[3])));
      float g1 = tanhf(pv1[0] + q1[0]);
      float i1 = 1.f / (1.f + expf(-(pv1[1] + q1[1])));
      float f1 = 1.f / (1.f + expf(-(pv1[2] + q1[2])));
      float o1 = 1.f / (1.f + expf(-(pv1[3] + q1[3])));
      c0 = g0 * i0 + c0 * f0;
      c1 = g1 * i1 + c1 * f1;
      float hv0 = tanhf(c0) * o0;
      float hv1 = tanhf(c1) * o1;
      union { _Float16 h[2]; unsigned int u; } pk;
      pk.h[0] = (_Float16)hv0;
      pk.h[1] = (_Float16)hv1;
      // device-coherent store (sc1): no dirty L2 line, no wbl2 needed
      __hip_atomic_store((unsigned int*)&hn[urow * 1024 + ug0], pk.u,
                         __ATOMIC_RELAXED, __HIP_MEMORY_SCOPE_AGENT);
      if (t == T_STEPS - 1) {
        h32[urow * 1024 + ug0] = hv0;
        h32[urow * 1024 + ug0 + 1] = hv1;
      }
    }
    if (t == T_STEPS - 1) break;  // no final barrier needed

    __syncthreads();  // vmcnt(0) drain: all waves' sc1 stores ack'd at coherence point
    if (tid == 0)
      __hip_atomic_store(&flags[blk * FLAG_STRIDE], (unsigned int)(t + 1),
                         __ATOMIC_RELAXED, __HIP_MEMORY_SCOPE_AGENT);
    if (tid < 128) {
      while (__hip_atomic_load(&flags[tid * FLAG_STRIDE], __ATOMIC_RELAXED,
                               __HIP_MEMORY_SCOPE_AGENT) < (unsigned int)(t + 1)) {
        __builtin_amdgcn_s_sleep(1);
      }
    }
    __syncthreads();
    // acquire: drop stale (clean) hbuf lines from L1/L2; every wave executes it
    __builtin_amdgcn_fence(__ATOMIC_ACQUIRE, "agent");
  }
}

// ---------------- final projection p = h_T @ W_ph + b_p (fp32)
__global__ void proj(const float* __restrict__ h32, const float* __restrict__ Wph,
                     const float* __restrict__ bp, float* __restrict__ logits) {
  const int b = blockIdx.x >> 1;
  const int cc = (blockIdx.x & 1) * 256 + threadIdx.x;
  const float* hrow = h32 + b * 1024;
  float acc = bp[cc];
#pragma unroll 4
  for (int k = 0; k < 1024; k++) acc += hrow[k] * Wph[k * 512 + cc];
  logits[b * 512 + cc] = acc;
}

// ---------------- row-wise log_softmax
__global__ void lsm(const float* __restrict__ logits, float* __restrict__ out) {
  const int b = blockIdx.x;
  const int tid = threadIdx.x;
  __shared__ float sm[4];
  __shared__ float se[4];
  float v0 = logits[b * 512 + tid];
  float v1 = logits[b * 512 + 256 + tid];
  float m = fmaxf(v0, v1);
  for (int o = 1; o < 64; o <<= 1) m = fmaxf(m, __shfl_xor(m, o, 64));
  if ((tid & 63) == 0) sm[tid >> 6] = m;
  __syncthreads();
  m = fmaxf(fmaxf(sm[0], sm[1]), fmaxf(sm[2], sm[3]));
  float e = expf(v0 - m) + expf(v1 - m);
  for (int o = 1; o < 64; o <<= 1) e += __shfl_xor(e, o, 64);
  if ((tid & 63) == 0) se[tid >> 6] = e;
  __syncthreads();
  float ls = logf(se[0] + se[1] + se[2] + se[3]) + m;
  out[b * 512 + tid] = v0 - ls;
  out[b * 512 + 256 + tid] = v1 - ls;
}

extern "C" void kernel_launch(void* const* d_in, const int* in_sizes, int n_in,
                              void* d_out, int out_size, void* d_ws, size_t ws_size,
                              hipStream_t stream) {
  const int* x = (const int*)d_in[0];
  const float* emb = (const float*)d_in[1];
  const float* Wgx = (const float*)d_in[2];
  const float* Wgh = (const float*)d_in[3];
  const float* bg = (const float*)d_in[4];
  const float* Wix = (const float*)d_in[5];
  const float* Wih = (const float*)d_in[6];
  const float* bi = (const float*)d_in[7];
  const float* Wfx = (const float*)d_in[8];
  const float* Wfh = (const float*)d_in[9];
  const float* bf = (const float*)d_in[10];
  const float* Wox = (const float*)d_in[11];
  const float* Woh = (const float*)d_in[12];
  const float* bo = (const float*)d_in[13];
  const float* Wph = (const float*)d_in[14];
  const float* bp = (const float*)d_in[15];
  const float* h_init = (const float*)d_in[16];
  const float* c_init = (const float*)d_in[17];

  char* ws = (char*)d_ws;
  float* P = (float*)ws;                                   // 520*4096*4   = 8,519,680
  unsigned int* flags = (unsigned int*)(ws + (size_t)513 * 4096 * 4);  // in P pad rows
  _Float16* Wt = (_Float16*)(ws + 8519680);                // 4096*1024*2  = 8,388,608
  _Float16* hbuf = (_Float16*)(ws + 8519680 + 8388608);    // 2*128*1024*2 = 524,288
  float* h32 = (float*)(ws + 8519680 + 8388608 + 524288);  // 128*1024*4   = 524,288
  float* logits = (float*)(ws + 8519680 + 8388608 + 524288 + 524288);  // 128*512*4

  pack_P<<<dim3(65, 16), 256, 0, stream>>>(emb, Wgx, Wix, Wfx, Wox, bg, bi, bf, bo, P);
  pack_Wt<<<4096, 256, 0, stream>>>(Wgh, Wih, Wfh, Woh, Wt);

  void* args[] = {(void*)&x, (void*)&P, (void*)&Wt, (void*)&hbuf,
                  (void*)&h32, (void*)&h_init, (void*)&c_init, (void*)&flags};
  hipLaunchCooperativeKernel((void*)lstm_step_all, dim3(NBLK), dim3(512), args, 0, stream);

  proj<<<256, 256, 0, stream>>>(h32, Wph, bp, logits);
  lsm<<<128, 256, 0, stream>>>(logits, (float*)d_out);
}

// Round 4
// 8642.907 us; speedup vs baseline: 1.0141x; 1.0141x over previous
//
#include <hip/hip_runtime.h>
#include <hip/hip_cooperative_groups.h>
#include <cmath>

namespace cg = cooperative_groups;

#define T_STEPS 512
#define NBLK 128
#define FLAG_STRIDE 16  // 64B-padded flag slots

typedef _Float16 h8 __attribute__((ext_vector_type(8)));
typedef float f4 __attribute__((ext_vector_type(4)));

union AFrag { unsigned long long u[2]; h8 v; };

// ---------------- pack P = emb @ [Wx interleaved] + bias : [513][4096] fp32 (exact input path)
__global__ void pack_P(const float* __restrict__ emb,
                       const float* __restrict__ Wgx, const float* __restrict__ Wix,
                       const float* __restrict__ Wfx, const float* __restrict__ Wox,
                       const float* __restrict__ bg, const float* __restrict__ bi,
                       const float* __restrict__ bf_, const float* __restrict__ bo,
                       float* __restrict__ P) {
  __shared__ float es[8][512];
  const int vg = blockIdx.x;   // 0..64
  const int st = blockIdx.y;   // 0..15
  const int tid = threadIdx.x;
  for (int i = tid; i < 8 * 512; i += 256) {
    int vv = i >> 9, k = i & 511;
    int v = vg * 8 + vv;
    es[vv][k] = (v < 513) ? emb[v * 512 + k] : 0.f;
  }
  __syncthreads();
  const int c = st * 256 + tid;
  const int gate = c & 3, unit = c >> 2;
  const float* W = gate == 0 ? Wgx : gate == 1 ? Wix : gate == 2 ? Wfx : Wox;
  const float* bias = gate == 0 ? bg : gate == 1 ? bi : gate == 2 ? bf_ : bo;
  float acc[8];
  const float bv = bias[unit];
#pragma unroll
  for (int vv = 0; vv < 8; vv++) acc[vv] = bv;
  for (int k = 0; k < 512; k++) {
    float w = W[k * 1024 + unit];
#pragma unroll
    for (int vv = 0; vv < 8; vv++) acc[vv] += es[vv][k] * w;
  }
#pragma unroll
  for (int vv = 0; vv < 8; vv++) {
    int v = vg * 8 + vv;
    if (v < 513) P[(size_t)v * 4096 + c] = acc[vv];
  }
}

// ---------------- pack Wt[c][k] = W_{gate(c)}h[k][unit(c)] as fp16
__global__ void pack_Wt(const float* __restrict__ Wgh, const float* __restrict__ Wih,
                        const float* __restrict__ Wfh, const float* __restrict__ Woh,
                        _Float16* __restrict__ Wt) {
  const int c = blockIdx.x;
  const int gate = c & 3, unit = c >> 2;
  const float* W = gate == 0 ? Wgh : gate == 1 ? Wih : gate == 2 ? Wfh : Woh;
  for (int k = threadIdx.x; k < 1024; k += 256)
    Wt[(size_t)c * 1024 + k] = (_Float16)W[k * 1024 + unit];
}

// A-group load: 8 chunks' A fragments (block-rotated chunk order), agent-coherent
#define LOADG(DST, G)                                                              \
  {                                                                                \
    _Pragma("unroll") for (int u = 0; u < 8; ++u) {                                \
      int j = (blk + 8 * (G) + u) & 31;                                            \
      int idx = 8 * j + (kg >> 2);                                                 \
      DST[u].u[0] = __hip_atomic_load(&a64[idx], __ATOMIC_RELAXED,                 \
                                      __HIP_MEMORY_SCOPE_AGENT);                   \
      DST[u].u[1] = __hip_atomic_load(&a64[idx + 1], __ATOMIC_RELAXED,             \
                                      __HIP_MEMORY_SCOPE_AGENT);                   \
    }                                                                              \
  }

#define COMPG(SRC, G)                                                              \
  {                                                                                \
    _Pragma("unroll") for (int u = 0; u < 8; ++u) {                                \
      int j = (blk + 8 * (G) + u) & 31;                                            \
      int kc = 32 * j;                                                             \
      h8 b0 = *(const h8*)&wlds[l15 * 1024 + ((kg + kc) ^ bx)];                    \
      h8 b1 = *(const h8*)&wlds[(l15 + 16) * 1024 + ((kg + kc) ^ bx)];             \
      acc0 = __builtin_amdgcn_mfma_f32_16x16x32_f16(SRC[u].v, b0, acc0, 0, 0, 0);  \
      acc1 = __builtin_amdgcn_mfma_f32_16x16x32_f16(SRC[u].v, b1, acc1, 0, 0, 0);  \
    }                                                                              \
  }

// Confirm first NEED rotated chunks published (flag >= t). nconf = prefix/4.
#define CONFIRM(NEED)                                                              \
  while (nconf < (NEED)) {                                                         \
    unsigned f0 = __hip_atomic_load(&flags[fb0 * FLAG_STRIDE], __ATOMIC_RELAXED,   \
                                    __HIP_MEMORY_SCOPE_AGENT);                     \
    unsigned f1 = __hip_atomic_load(&flags[fb1 * FLAG_STRIDE], __ATOMIC_RELAXED,   \
                                    __HIP_MEMORY_SCOPE_AGENT);                     \
    unsigned long long n0 = ~__ballot(f0 >= tt);                                   \
    unsigned long long n1 = ~__ballot(f1 >= tt);                                   \
    unsigned pre_ = n0 ? (unsigned)__builtin_ctzll(n0)                             \
                       : (n1 ? 64u + (unsigned)__builtin_ctzll(n1) : 128u);        \
    nconf = pre_ >> 2;                                                             \
    if (nconf < (NEED)) __builtin_amdgcn_s_sleep(1);                               \
  }

// ---------------- persistent LSTM: 128 blocks x 512 threads, NO global barrier.
// Per-chunk dataflow: chunk j (h cols [32j,32j+32)) is gated on flags of its 4
// producer blocks only, consumed in block-rotated order (own chunk first).
// Safety (double buffer, no fences):
//  - flag[S]=v certifies S finished all reads of h_{v-1} and drained sc1 writes
//    of h_v to LLC (stores -> syncthreads vmcnt drain -> flag store).
//  - A block writes h_{t+1} (buffer (t+1)&1, previously h_{t-1}) only after
//    consuming all 32 chunks of h_t, i.e. all flags >= t, i.e. nobody still
//    reads h_{t-1}.  Reads are agent-scope atomic loads (LLC-coherent).
__launch_bounds__(512)
__global__ void lstm_step_all(const int* __restrict__ x,
                              const float* __restrict__ P,
                              const _Float16* __restrict__ Wt,
                              _Float16* __restrict__ hbuf,
                              float* __restrict__ h32,
                              const float* __restrict__ h_init,
                              const float* __restrict__ c_init,
                              unsigned int* __restrict__ flags) {
  cg::grid_group grid = cg::this_grid();
  __shared__ _Float16 wlds[32 * 1024];  // 64 KB
  __shared__ float prebuf[128][44];     // 22.5 KB, 16B-aligned rows (176B stride)
  __shared__ int xs2[2][128];
  const int tid = threadIdx.x;
  const int blk = blockIdx.x;
  const int lane = tid & 63;
  const int wid = tid >> 6;
  const int colbase = blk * 32;

  if (tid == 0)
    __hip_atomic_store(&flags[blk * FLAG_STRIDE], 0u, __ATOMIC_RELAXED, __HIP_MEMORY_SCOPE_AGENT);

  // stage time-invariant B slice into LDS (granule-XOR layout)
  for (int i = tid; i < 32 * 128; i += 512) {
    int c = i >> 7, g = i & 127;
    *(h8*)&wlds[c * 1024 + ((g * 8) ^ ((c & 7) * 8))] =
        *(const h8*)&Wt[(size_t)(colbase + c) * 1024 + g * 8];
  }

  // per-thread persistent c state: thread owns (row=tid>>2, units 2*(tid&3)+{0,1})
  const int urow = tid >> 2;
  const int upair = tid & 3;
  const int ug0 = blk * 8 + upair * 2;
  float c0 = c_init[ug0], c1 = c_init[ug0 + 1];
  {
    union { _Float16 h[2]; unsigned int u; } pk;
    pk.h[0] = (_Float16)h_init[ug0];
    pk.h[1] = (_Float16)h_init[ug0 + 1];
    *(unsigned int*)&hbuf[urow * 1024 + ug0] = pk.u;  // buffer 0 (flushed by grid.sync)
  }
  if (tid < 128) xs2[0][tid] = x[tid * 513 + 0];
  grid.sync();  // once at init: covers h0, wlds, flag reset

  const int l15 = lane & 15;
  const int kg = (lane >> 4) * 8;
  const int arow = wid * 16 + l15;
  const int bx = (l15 & 7) * 8;
  const int fb0 = (4 * blk + lane) & 127;        // rotated flag order, own block first
  const int fb1 = (4 * blk + 64 + lane) & 127;

  AFrag Ab[8], Bb[8];

  for (int t = 0; t < T_STEPS; t++) {
    const _Float16* hc = hbuf + (t & 1) * (128 * 1024);
    _Float16* hn = hbuf + ((t + 1) & 1) * (128 * 1024);
    const unsigned long long* a64 = (const unsigned long long*)(hc + (size_t)arow * 1024);
    const unsigned tt = (unsigned)t;

    // exact-P gather (plain loads; L2 stays warm — no invalidations anywhere)
    const float* prow = P + (size_t)xs2[t & 1][urow] * 4096 + colbase + upair * 8;
    f4 pv0 = *(const f4*)(prow);
    f4 pv1 = *(const f4*)(prow + 4);

    f4 acc0 = {0.f, 0.f, 0.f, 0.f}, acc1 = {0.f, 0.f, 0.f, 0.f};
    unsigned nconf = 0;

    // pipelined chunk consumption: confirm -> load group g+1 -> compute group g
    CONFIRM(8u);  LOADG(Ab, 0);
    CONFIRM(16u); LOADG(Bb, 1);
    COMPG(Ab, 0);
    CONFIRM(24u); LOADG(Ab, 2);
    COMPG(Bb, 1);
    CONFIRM(32u); LOADG(Bb, 3);
    COMPG(Ab, 2);
    COMPG(Bb, 3);

#pragma unroll
    for (int r = 0; r < 4; r++) {
      int row = wid * 16 + (lane >> 4) * 4 + r;
      prebuf[row][l15] = acc0[r];
      prebuf[row][l15 + 16] = acc1[r];
    }
    if (t + 1 < T_STEPS && tid < 128) xs2[(t + 1) & 1][tid] = x[tid * 513 + (t + 1)];
    __syncthreads();

    // gate nonlinearity + state update
    {
      f4 q0 = *(const f4*)&prebuf[urow][upair * 8];
      f4 q1 = *(const f4*)&prebuf[urow][upair * 8 + 4];
      float g0 = tanhf(pv0[0] + q0[0]);
      float i0 = 1.f / (1.f + expf(-(pv0[1] + q0[1])));
      float f0 = 1.f / (1.f + expf(-(pv0[2] + q0[2])));
      float o0 = 1.f / (1.f + expf(-(pv0[3] + q0[3])));
      float g1 = tanhf(pv1[0] + q1[0]);
      float i1 = 1.f / (1.f + expf(-(pv1[1] + q1[1])));
      float f1 = 1.f / (1.f + expf(-(pv1[2] + q1[2])));
      float o1 = 1.f / (1.f + expf(-(pv1[3] + q1[3])));
      c0 = g0 * i0 + c0 * f0;
      c1 = g1 * i1 + c1 * f1;
      float hv0 = tanhf(c0) * o0;
      float hv1 = tanhf(c1) * o1;
      union { _Float16 h[2]; unsigned int u; } pk;
      pk.h[0] = (_Float16)hv0;
      pk.h[1] = (_Float16)hv1;
      __hip_atomic_store((unsigned int*)&hn[urow * 1024 + ug0], pk.u,
                         __ATOMIC_RELAXED, __HIP_MEMORY_SCOPE_AGENT);
      if (t == T_STEPS - 1) {
        h32[urow * 1024 + ug0] = hv0;
        h32[urow * 1024 + ug0 + 1] = hv1;
      }
    }
    if (t == T_STEPS - 1) break;

    __syncthreads();  // vmcnt drain: all h stores ack'd at LLC before publish
    if (tid == 0)
      __hip_atomic_store(&flags[blk * FLAG_STRIDE], (unsigned int)(t + 1),
                         __ATOMIC_RELAXED, __HIP_MEMORY_SCOPE_AGENT);
  }
}

// ---------------- final projection p = h_T @ W_ph + b_p (fp32)
__global__ void proj(const float* __restrict__ h32, const float* __restrict__ Wph,
                     const float* __restrict__ bp, float* __restrict__ logits) {
  const int b = blockIdx.x >> 1;
  const int cc = (blockIdx.x & 1) * 256 + threadIdx.x;
  const float* hrow = h32 + b * 1024;
  float acc = bp[cc];
#pragma unroll 4
  for (int k = 0; k < 1024; k++) acc += hrow[k] * Wph[k * 512 + cc];
  logits[b * 512 + cc] = acc;
}

// ---------------- row-wise log_softmax
__global__ void lsm(const float* __restrict__ logits, float* __restrict__ out) {
  const int b = blockIdx.x;
  const int tid = threadIdx.x;
  __shared__ float sm[4];
  __shared__ float se[4];
  float v0 = logits[b * 512 + tid];
  float v1 = logits[b * 512 + 256 + tid];
  float m = fmaxf(v0, v1);
  for (int o = 1; o < 64; o <<= 1) m = fmaxf(m, __shfl_xor(m, o, 64));
  if ((tid & 63) == 0) sm[tid >> 6] = m;
  __syncthreads();
  m = fmaxf(fmaxf(sm[0], sm[1]), fmaxf(sm[2], sm[3]));
  float e = expf(v0 - m) + expf(v1 - m);
  for (int o = 1; o < 64; o <<= 1) e += __shfl_xor(e, o, 64);
  if ((tid & 63) == 0) se[tid >> 6] = e;
  __syncthreads();
  float ls = logf(se[0] + se[1] + se[2] + se[3]) + m;
  out[b * 512 + tid] = v0 - ls;
  out[b * 512 + 256 + tid] = v1 - ls;
}

extern "C" void kernel_launch(void* const* d_in, const int* in_sizes, int n_in,
                              void* d_out, int out_size, void* d_ws, size_t ws_size,
                              hipStream_t stream) {
  const int* x = (const int*)d_in[0];
  const float* emb = (const float*)d_in[1];
  const float* Wgx = (const float*)d_in[2];
  const float* Wgh = (const float*)d_in[3];
  const float* bg = (const float*)d_in[4];
  const float* Wix = (const float*)d_in[5];
  const float* Wih = (const float*)d_in[6];
  const float* bi = (const float*)d_in[7];
  const float* Wfx = (const float*)d_in[8];
  const float* Wfh = (const float*)d_in[9];
  const float* bf = (const float*)d_in[10];
  const float* Wox = (const float*)d_in[11];
  const float* Woh = (const float*)d_in[12];
  const float* bo = (const float*)d_in[13];
  const float* Wph = (const float*)d_in[14];
  const float* bp = (const float*)d_in[15];
  const float* h_init = (const float*)d_in[16];
  const float* c_init = (const float*)d_in[17];

  char* ws = (char*)d_ws;
  float* P = (float*)ws;                                   // 520*4096*4   = 8,519,680
  unsigned int* flags = (unsigned int*)(ws + (size_t)513 * 4096 * 4);  // in P pad rows
  _Float16* Wt = (_Float16*)(ws + 8519680);                // 4096*1024*2  = 8,388,608
  _Float16* hbuf = (_Float16*)(ws + 8519680 + 8388608);    // 2*128*1024*2 = 524,288
  float* h32 = (float*)(ws + 8519680 + 8388608 + 524288);  // 128*1024*4   = 524,288
  float* logits = (float*)(ws + 8519680 + 8388608 + 524288 + 524288);  // 128*512*4

  pack_P<<<dim3(65, 16), 256, 0, stream>>>(emb, Wgx, Wix, Wfx, Wox, bg, bi, bf, bo, P);
  pack_Wt<<<4096, 256, 0, stream>>>(Wgh, Wih, Wfh, Woh, Wt);

  void* args[] = {(void*)&x, (void*)&P, (void*)&Wt, (void*)&hbuf,
                  (void*)&h32, (void*)&h_init, (void*)&c_init, (void*)&flags};
  hipLaunchCooperativeKernel((void*)lstm_step_all, dim3(NBLK), dim3(512), args, 0, stream);

  proj<<<256, 256, 0, stream>>>(h32, Wph, bp, logits);
  lsm<<<128, 256, 0, stream>>>(logits, (float*)d_out);
}

// Round 5
// 5916.123 us; speedup vs baseline: 1.4815x; 1.4609x over previous
//
#include <hip/hip_runtime.h>
#include <hip/hip_cooperative_groups.h>
#include <cmath>

namespace cg = cooperative_groups;

#define T_STEPS 512
#define NBLK 64
#define FLAG_STRIDE 16  // 64B-padded flag slots

typedef _Float16 h8 __attribute__((ext_vector_type(8)));
typedef float f4 __attribute__((ext_vector_type(4)));

// ---------------- pack P = emb @ [Wx interleaved] + bias : [513][4096] fp32 (exact input path)
__global__ void pack_P(const float* __restrict__ emb,
                       const float* __restrict__ Wgx, const float* __restrict__ Wix,
                       const float* __restrict__ Wfx, const float* __restrict__ Wox,
                       const float* __restrict__ bg, const float* __restrict__ bi,
                       const float* __restrict__ bf_, const float* __restrict__ bo,
                       float* __restrict__ P) {
  __shared__ float es[8][512];
  const int vg = blockIdx.x;   // 0..64
  const int st = blockIdx.y;   // 0..15
  const int tid = threadIdx.x;
  for (int i = tid; i < 8 * 512; i += 256) {
    int vv = i >> 9, k = i & 511;
    int v = vg * 8 + vv;
    es[vv][k] = (v < 513) ? emb[v * 512 + k] : 0.f;
  }
  __syncthreads();
  const int c = st * 256 + tid;
  const int gate = c & 3, unit = c >> 2;
  const float* W = gate == 0 ? Wgx : gate == 1 ? Wix : gate == 2 ? Wfx : Wox;
  const float* bias = gate == 0 ? bg : gate == 1 ? bi : gate == 2 ? bf_ : bo;
  float acc[8];
  const float bv = bias[unit];
#pragma unroll
  for (int vv = 0; vv < 8; vv++) acc[vv] = bv;
  for (int k = 0; k < 512; k++) {
    float w = W[k * 1024 + unit];
#pragma unroll
    for (int vv = 0; vv < 8; vv++) acc[vv] += es[vv][k] * w;
  }
#pragma unroll
  for (int vv = 0; vv < 8; vv++) {
    int v = vg * 8 + vv;
    if (v < 513) P[(size_t)v * 4096 + c] = acc[vv];
  }
}

// ---------------- pack Wt[c][k] = W_{gate(c)}h[k][unit(c)] as fp16
__global__ void pack_Wt(const float* __restrict__ Wgh, const float* __restrict__ Wih,
                        const float* __restrict__ Wfh, const float* __restrict__ Woh,
                        _Float16* __restrict__ Wt) {
  const int c = blockIdx.x;
  const int gate = c & 3, unit = c >> 2;
  const float* W = gate == 0 ? Wgh : gate == 1 ? Wih : gate == 2 ? Wfh : Woh;
  for (int k = threadIdx.x; k < 1024; k += 256)
    Wt[(size_t)c * 1024 + k] = (_Float16)W[k * 1024 + unit];
}

// ---------------- persistent LSTM: 64 blocks x 512 threads (64 gate-cols per block,
// full W-slice in LDS). Sync protocol = R2's proven one: sc1 h-stores ->
// syncthreads (vmcnt drain) -> relaxed flag -> spin -> syncthreads ->
// wave0-only agent-acquire fence (invalidates the block's L1+L2 once) -> syncthreads.
// Plain cacheable A-loads: blocks sharing an XCD share the post-inv L2 refill.
__launch_bounds__(512)
__global__ void lstm_step_all(const int* __restrict__ x,
                              const float* __restrict__ P,
                              const _Float16* __restrict__ Wt,
                              _Float16* __restrict__ hbuf,
                              float* __restrict__ h32,
                              const float* __restrict__ h_init,
                              const float* __restrict__ c_init,
                              unsigned int* __restrict__ flags) {
  cg::grid_group grid = cg::this_grid();
  __shared__ _Float16 wlds[64 * 1024];   // 128 KB, XOR-swizzled 16B granules
  __shared__ _Float16 pre[128][72];      // 18 KB fp16 pre-activations (stride 144B, 16B-aligned)
  __shared__ int xs2[2][128];
  const int tid = threadIdx.x;
  const int blk = blockIdx.x;  // 0..63
  const int lane = tid & 63;
  const int wid = tid >> 6;    // 0..7
  const int colbase = blk * 64;

  if (tid == 0)
    __hip_atomic_store(&flags[blk * FLAG_STRIDE], 0u, __ATOMIC_RELAXED, __HIP_MEMORY_SCOPE_AGENT);

  // stage time-invariant B slice (64 cols x 1024 k) into LDS, granule-XOR layout:
  // element (c,k) at wlds[c*1024 + (k ^ ((c&7)*8))]
  for (int i = tid; i < 64 * 128; i += 512) {
    int c = i >> 7, g = i & 127;
    *(h8*)&wlds[c * 1024 + ((g * 8) ^ ((c & 7) * 8))] =
        *(const h8*)&Wt[(size_t)(colbase + c) * 1024 + g * 8];
  }

  // per-thread state: thread owns row = tid>>2, local units (tid&3)*4 + {0..3}
  const int urow = tid >> 2;
  const int ul0 = (tid & 3) * 4;        // local unit base (0..12)
  const int gu0 = blk * 16 + ul0;       // global unit base
  float cs[4];
#pragma unroll
  for (int u = 0; u < 4; u++) cs[u] = c_init[gu0 + u];
  {
    union { _Float16 h[4]; unsigned long long u; } pk;
#pragma unroll
    for (int u = 0; u < 4; u++) pk.h[u] = (_Float16)h_init[gu0 + u];
    *(unsigned long long*)&hbuf[urow * 1024 + gu0] = pk.u;  // buffer 0
  }
  if (tid < 128) xs2[0][tid] = x[tid * 513 + 0];
  grid.sync();  // once at init: covers h0, wlds, flag reset

  const int l15 = lane & 15;
  const int kg = (lane >> 4) * 8;
  const int arow = wid * 16 + l15;

  for (int t = 0; t < T_STEPS; t++) {
    const _Float16* hc = hbuf + (t & 1) * (128 * 1024);
    _Float16* hn = hbuf + ((t + 1) & 1) * (128 * 1024);

    // exact-P gather issued early; used in gate phase (latency hides under MFMA)
    const float* prow = P + (size_t)xs2[t & 1][urow] * 4096 + colbase + ul0 * 4;
    f4 pv0 = *(const f4*)(prow);
    f4 pv1 = *(const f4*)(prow + 4);
    f4 pv2 = *(const f4*)(prow + 8);
    f4 pv3 = *(const f4*)(prow + 12);

    // recurrent GEMM: wave computes 16 rows x 64 cols, K=1024 (128 MFMA)
    f4 a0 = {0.f, 0.f, 0.f, 0.f}, a1 = a0, a2 = a0, a3 = a0;
    const _Float16* ap = hc + arow * 1024 + kg;
#pragma unroll 4
    for (int k0 = 0; k0 < 1024; k0 += 32) {
      h8 a = *(const h8*)(ap + k0);
      int kk = kg + k0;
      h8 b0 = *(const h8*)&wlds[(l15 + 0) * 1024 + (kk ^ ((l15 & 7) * 8))];
      h8 b1 = *(const h8*)&wlds[(l15 + 16) * 1024 + (kk ^ ((l15 & 7) * 8))];
      h8 b2 = *(const h8*)&wlds[(l15 + 32) * 1024 + (kk ^ ((l15 & 7) * 8))];
      h8 b3 = *(const h8*)&wlds[(l15 + 48) * 1024 + (kk ^ ((l15 & 7) * 8))];
      a0 = __builtin_amdgcn_mfma_f32_16x16x32_f16(a, b0, a0, 0, 0, 0);
      a1 = __builtin_amdgcn_mfma_f32_16x16x32_f16(a, b1, a1, 0, 0, 0);
      a2 = __builtin_amdgcn_mfma_f32_16x16x32_f16(a, b2, a2, 0, 0, 0);
      a3 = __builtin_amdgcn_mfma_f32_16x16x32_f16(a, b3, a3, 0, 0, 0);
    }

    // scatter pre-activations to LDS (fp16)
#pragma unroll
    for (int r = 0; r < 4; r++) {
      int row = wid * 16 + (lane >> 4) * 4 + r;
      pre[row][l15 + 0] = (_Float16)a0[r];
      pre[row][l15 + 16] = (_Float16)a1[r];
      pre[row][l15 + 32] = (_Float16)a2[r];
      pre[row][l15 + 48] = (_Float16)a3[r];
    }
    if (t + 1 < T_STEPS && tid < 128) xs2[(t + 1) & 1][tid] = x[tid * 513 + (t + 1)];
    __syncthreads();

    // gate nonlinearity + state update: 4 units per thread
    {
      h8 q0 = *(const h8*)&pre[urow][ul0 * 4];      // 8 fp16: units ul0,ul0+1 (g,i,f,o each)
      h8 q1 = *(const h8*)&pre[urow][ul0 * 4 + 8];  // units ul0+2, ul0+3
      float hv[4];
#pragma unroll
      for (int u = 0; u < 4; u++) {
        f4 pv = u == 0 ? pv0 : u == 1 ? pv1 : u == 2 ? pv2 : pv3;
        float qg = (u < 2) ? (float)q0[(u & 1) * 4 + 0] : (float)q1[(u & 1) * 4 + 0];
        float qi = (u < 2) ? (float)q0[(u & 1) * 4 + 1] : (float)q1[(u & 1) * 4 + 1];
        float qf = (u < 2) ? (float)q0[(u & 1) * 4 + 2] : (float)q1[(u & 1) * 4 + 2];
        float qo = (u < 2) ? (float)q0[(u & 1) * 4 + 3] : (float)q1[(u & 1) * 4 + 3];
        float g = tanhf(pv[0] + qg);
        float i = 1.f / (1.f + expf(-(pv[1] + qi)));
        float f = 1.f / (1.f + expf(-(pv[2] + qf)));
        float o = 1.f / (1.f + expf(-(pv[3] + qo)));
        cs[u] = g * i + cs[u] * f;
        hv[u] = tanhf(cs[u]) * o;
      }
      union { _Float16 h[4]; unsigned long long u; } pk;
#pragma unroll
      for (int u = 0; u < 4; u++) pk.h[u] = (_Float16)hv[u];
      // sc1 write-through: visible at LLC for other XCDs, updates local L2
      __hip_atomic_store((unsigned long long*)&hn[urow * 1024 + gu0], pk.u,
                         __ATOMIC_RELAXED, __HIP_MEMORY_SCOPE_AGENT);
      if (t == T_STEPS - 1) {
        f4 hw = {hv[0], hv[1], hv[2], hv[3]};
        *(f4*)&h32[urow * 1024 + gu0] = hw;
      }
    }
    if (t == T_STEPS - 1) break;

    __syncthreads();  // vmcnt drain: all waves' sc1 stores ack'd before publish
    if (tid == 0)
      __hip_atomic_store(&flags[blk * FLAG_STRIDE], (unsigned int)(t + 1),
                         __ATOMIC_RELAXED, __HIP_MEMORY_SCOPE_AGENT);
    if (tid < NBLK) {
      while (__hip_atomic_load(&flags[tid * FLAG_STRIDE], __ATOMIC_RELAXED,
                               __HIP_MEMORY_SCOPE_AGENT) < (unsigned int)(t + 1)) {
        __builtin_amdgcn_s_sleep(1);
      }
    }
    __syncthreads();
    // acquire once per block (wave 0): L1+L2 inv covers the whole CU/XCD
    if (wid == 0) __builtin_amdgcn_fence(__ATOMIC_ACQUIRE, "agent");
    __syncthreads();
  }
}

// ---------------- final projection p = h_T @ W_ph + b_p (fp32)
__global__ void proj(const float* __restrict__ h32, const float* __restrict__ Wph,
                     const float* __restrict__ bp, float* __restrict__ logits) {
  const int b = blockIdx.x >> 1;
  const int cc = (blockIdx.x & 1) * 256 + threadIdx.x;
  const float* hrow = h32 + b * 1024;
  float acc = bp[cc];
#pragma unroll 4
  for (int k = 0; k < 1024; k++) acc += hrow[k] * Wph[k * 512 + cc];
  logits[b * 512 + cc] = acc;
}

// ---------------- row-wise log_softmax
__global__ void lsm(const float* __restrict__ logits, float* __restrict__ out) {
  const int b = blockIdx.x;
  const int tid = threadIdx.x;
  __shared__ float sm[4];
  __shared__ float se[4];
  float v0 = logits[b * 512 + tid];
  float v1 = logits[b * 512 + 256 + tid];
  float m = fmaxf(v0, v1);
  for (int o = 1; o < 64; o <<= 1) m = fmaxf(m, __shfl_xor(m, o, 64));
  if ((tid & 63) == 0) sm[tid >> 6] = m;
  __syncthreads();
  m = fmaxf(fmaxf(sm[0], sm[1]), fmaxf(sm[2], sm[3]));
  float e = expf(v0 - m) + expf(v1 - m);
  for (int o = 1; o < 64; o <<= 1) e += __shfl_xor(e, o, 64);
  if ((tid & 63) == 0) se[tid >> 6] = e;
  __syncthreads();
  float ls = logf(se[0] + se[1] + se[2] + se[3]) + m;
  out[b * 512 + tid] = v0 - ls;
  out[b * 512 + 256 + tid] = v1 - ls;
}

extern "C" void kernel_launch(void* const* d_in, const int* in_sizes, int n_in,
                              void* d_out, int out_size, void* d_ws, size_t ws_size,
                              hipStream_t stream) {
  const int* x = (const int*)d_in[0];
  const float* emb = (const float*)d_in[1];
  const float* Wgx = (const float*)d_in[2];
  const float* Wgh = (const float*)d_in[3];
  const float* bg = (const float*)d_in[4];
  const float* Wix = (const float*)d_in[5];
  const float* Wih = (const float*)d_in[6];
  const float* bi = (const float*)d_in[7];
  const float* Wfx = (const float*)d_in[8];
  const float* Wfh = (const float*)d_in[9];
  const float* bf = (const float*)d_in[10];
  const float* Wox = (const float*)d_in[11];
  const float* Woh = (const float*)d_in[12];
  const float* bo = (const float*)d_in[13];
  const float* Wph = (const float*)d_in[14];
  const float* bp = (const float*)d_in[15];
  const float* h_init = (const float*)d_in[16];
  const float* c_init = (const float*)d_in[17];

  char* ws = (char*)d_ws;
  float* P = (float*)ws;                                   // 520*4096*4   = 8,519,680
  unsigned int* flags = (unsigned int*)(ws + (size_t)513 * 4096 * 4);  // in P pad rows
  _Float16* Wt = (_Float16*)(ws + 8519680);                // 4096*1024*2  = 8,388,608
  _Float16* hbuf = (_Float16*)(ws + 8519680 + 8388608);    // 2*128*1024*2 = 524,288
  float* h32 = (float*)(ws + 8519680 + 8388608 + 524288);  // 128*1024*4   = 524,288
  float* logits = (float*)(ws + 8519680 + 8388608 + 524288 + 524288);  // 128*512*4

  pack_P<<<dim3(65, 16), 256, 0, stream>>>(emb, Wgx, Wix, Wfx, Wox, bg, bi, bf, bo, P);
  pack_Wt<<<4096, 256, 0, stream>>>(Wgh, Wih, Wfh, Woh, Wt);

  void* args[] = {(void*)&x, (void*)&P, (void*)&Wt, (void*)&hbuf,
                  (void*)&h32, (void*)&h_init, (void*)&c_init, (void*)&flags};
  hipLaunchCooperativeKernel((void*)lstm_step_all, dim3(NBLK), dim3(512), args, 0, stream);

  proj<<<256, 256, 0, stream>>>(h32, Wph, bp, logits);
  lsm<<<128, 256, 0, stream>>>(logits, (float*)d_out);
}